// Round 3
// baseline (124.886 us; speedup 1.0000x reference)
//
#include <hip/hip_runtime.h>
#include <hip/hip_bf16.h>

#define UNITS 128
#define NHEADS 8
#define DHEAD 16
#define SEQ 4096
#define BATCH 2
#define KVBLK 64
#define HALFLEN (SEQ / 2)          // 2048 keys per kv-half
#define NBLK2 (HALFLEN / KVBLK)    // 32 iterations
#define QSCALE 0.3606737602f       // d^-0.5 * log2(e): logits in log2 domain
#define MASKNEG -1e30f
#define MINIT   -1e4f

typedef __bf16 bf8 __attribute__((ext_vector_type(8)));
typedef __bf16 bf4 __attribute__((ext_vector_type(4)));
typedef __bf16 bf2 __attribute__((ext_vector_type(2)));
typedef float f4 __attribute__((ext_vector_type(4)));

#define KP 24   // K pitch (el): 48B rows, b128-aligned, bank-uniform; d 16..23 never read
#define VP 72   // V^T / P^T pitch (el): 144B rows, bank-uniform

__global__ __launch_bounds__(512, 8) void attn_fwd(
    const float* __restrict__ memory, const float* __restrict__ query,
    const int* __restrict__ seq_mask, float* __restrict__ out)
{
    const int bidx = blockIdx.z;
    const int h    = blockIdx.y;
    const int qblk = blockIdx.x;
    const int tid  = threadIdx.x;
    const int wave = tid >> 6;
    const int half = wave >> 2;    // kv half: waves 0-3 -> keys [0,2048), 4-7 -> [2048,4096)
    const int qw   = wave & 3;     // q sub-tile within the WG's 64 rows
    const int lane = tid & 63;
    const int col  = lane & 15;    // q (QK B-frag) / d (PV A-frag)
    const int g    = lane >> 4;

    __shared__ __bf16 Klds[2][2][KVBLK][KP];   // 12288 B
    __shared__ __bf16 Vt[2][2][DHEAD][VP];     //  9216 B
    __shared__ __bf16 Plds[8][16][VP];         // 18432 B (reused for the merge)
    __shared__ float  maskadd[2][2][KVBLK];    //  1024 B   -> total 40960 = 4 WG/CU

    // ---- Q fragment (B operand): k = g*8+j for g<2 (=d 0..15), zero for g>=2
    const int qrow = qblk * 64 + qw * 16 + col;
    bf8 qfrag;
    if (g < 2) {
        const float* qp = query + ((size_t)bidx * SEQ + qrow) * UNITS + h * DHEAD + g * 8;
        #pragma unroll
        for (int j = 0; j < 8; ++j) qfrag[j] = (__bf16)(qp[j] * QSCALE);
    } else {
        #pragma unroll
        for (int j = 0; j < 8; ++j) qfrag[j] = (__bf16)0.f;
    }

    bf8 ones;
    #pragma unroll
    for (int j = 0; j < 8; ++j) ones[j] = (__bf16)1.f;

    // ---- staging: 256 threads per kv-half (the half's own 4 waves)
    const int t256 = tid & 255;
    const int skey = t256 >> 2;
    const int sd   = (t256 & 3) * 4;
    const int vkp  = (t256 & 31) * 2;
    const int vd   = (t256 >> 5) * 2;

    const size_t mem_base = (size_t)bidx * SEQ * (2 * UNITS);
    const float* kptr = memory + mem_base + (size_t)(half * HALFLEN + skey) * (2 * UNITS) + h * DHEAD + sd;
    const float* vptr = memory + mem_base + (size_t)(half * HALFLEN + vkp) * (2 * UNITS) + h * DHEAD + UNITS + vd;
    const int*   mptr = seq_mask + (size_t)bidx * SEQ + half * HALFLEN + (t256 & 63);

    float4 kreg = *(const float4*)kptr;
    float2 va   = *(const float2*)vptr;
    float2 vb   = *(const float2*)(vptr + 2 * UNITS);
    int    mreg = (t256 < KVBLK) ? *mptr : 0;

    float m = MINIT;
    f4 acc  = {0.f, 0.f, 0.f, 0.f};
    f4 lacc = {0.f, 0.f, 0.f, 0.f};

    const int kele = (g & 1) * 8;   // g>=2 lanes re-read d 0..15 (finite, x0 in MFMA)

    for (int blk = 0; blk < NBLK2; ++blk) {
        const int buf = blk & 1;

        bf4 ks;
        ks[0] = (__bf16)kreg.x; ks[1] = (__bf16)kreg.y;
        ks[2] = (__bf16)kreg.z; ks[3] = (__bf16)kreg.w;
        *(bf4*)&Klds[half][buf][skey][sd] = ks;
        bf2 v0; v0[0] = (__bf16)va.x; v0[1] = (__bf16)vb.x;
        bf2 v1; v1[0] = (__bf16)va.y; v1[1] = (__bf16)vb.y;
        *(bf2*)&Vt[half][buf][vd][vkp]     = v0;
        *(bf2*)&Vt[half][buf][vd + 1][vkp] = v1;
        if (t256 < KVBLK) maskadd[half][buf][t256] = mreg ? 0.f : MASKNEG;

        __syncthreads();

        if (blk + 1 < NBLK2) {
            kptr += KVBLK * 2 * UNITS;
            vptr += KVBLK * 2 * UNITS;
            mptr += KVBLK;
            kreg = *(const float4*)kptr;
            va   = *(const float2*)vptr;
            vb   = *(const float2*)(vptr + 2 * UNITS);
            if (t256 < KVBLK) mreg = *mptr;
        }

        // ---- S^T: mfma(A=K, B=Q, C=mask) -> D[key][q]
        float sv[16];
        #pragma unroll
        for (int t = 0; t < 4; ++t) {
            bf8 kfrag = *(const bf8*)&Klds[half][buf][t * 16 + col][kele];
            f4 cma = *(const f4*)&maskadd[half][buf][t * 16 + g * 4];
            f4 s = __builtin_amdgcn_mfma_f32_16x16x32_bf16(kfrag, qfrag, cma, 0, 0, 0);
            sv[t * 4 + 0] = s[0]; sv[t * 4 + 1] = s[1];
            sv[t * 4 + 2] = s[2]; sv[t * 4 + 3] = s[3];
        }

        // ---- block max: v_max3 tree + 2 shfl
        float x0 = fmaxf(fmaxf(sv[0], sv[1]), sv[2]);
        float x1 = fmaxf(fmaxf(sv[3], sv[4]), sv[5]);
        float x2 = fmaxf(fmaxf(sv[6], sv[7]), sv[8]);
        float x3 = fmaxf(fmaxf(sv[9], sv[10]), sv[11]);
        float x4 = fmaxf(fmaxf(sv[12], sv[13]), sv[14]);
        float x5 = fmaxf(fmaxf(x0, x1), x2);
        float x6 = fmaxf(fmaxf(x3, x4), sv[15]);
        float bmax = fmaxf(x5, x6);
        bmax = fmaxf(bmax, __shfl_xor(bmax, 16));
        bmax = fmaxf(bmax, __shfl_xor(bmax, 32));

        // ---- T13 defer-max (log2 domain, thr 11 -> P <= 2048)
        if (!__all(bmax <= m + 11.0f)) {
            const float m_new = fmaxf(m, bmax);
            const float sc = exp2f(m - m_new);
            #pragma unroll
            for (int r = 0; r < 4; ++r) acc[r] *= sc;
            lacc[0] *= sc;
            m = m_new;
        }

        // ---- exp2 + pack P^T to per-wave LDS
        #pragma unroll
        for (int t = 0; t < 4; ++t) {
            #pragma unroll
            for (int rp = 0; rp < 2; ++rp) {
                bf2 pk;
                pk[0] = (__bf16)exp2f(sv[t * 4 + rp * 2 + 0] - m);
                pk[1] = (__bf16)exp2f(sv[t * 4 + rp * 2 + 1] - m);
                *(bf2*)&Plds[wave][col][t * 16 + g * 4 + rp * 2] = pk;
            }
        }

        // ---- PV + denominator on the MFMA pipe
        #pragma unroll
        for (int hh = 0; hh < 2; ++hh) {
            bf8 vfrag = *(const bf8*)&Vt[half][buf][col][hh * 32 + g * 8];
            bf8 pfrag = *(const bf8*)&Plds[wave][col][hh * 32 + g * 8];
            acc  = __builtin_amdgcn_mfma_f32_16x16x32_bf16(vfrag, pfrag, acc, 0, 0, 0);
            lacc = __builtin_amdgcn_mfma_f32_16x16x32_bf16(ones,  pfrag, lacc, 0, 0, 0);
        }
    }

    // ---- merge kv-halves through LDS (reuse Plds), then store
    __syncthreads();
    float* pbuf = (float*)&Plds[0][0][0];
    const int prow = (qw * 16 + col) * 20;
    if (half == 1) {
        *(f4*)&pbuf[prow + g * 4] = acc;
        if (g == 0) { pbuf[prow + 16] = m; pbuf[prow + 17] = lacc[0]; }
    }
    __syncthreads();
    if (half == 0) {
        const float m1 = pbuf[prow + 16];
        const float l1 = pbuf[prow + 17];
        f4 a1 = *(const f4*)&pbuf[prow + g * 4];
        const float M  = fmaxf(m, m1);
        const float w0 = exp2f(m - M);
        const float w1 = exp2f(m1 - M);
        const float invl = 1.0f / (lacc[0] * w0 + l1 * w1);
        float4 o;
        o.x = (acc[0] * w0 + a1[0] * w1) * invl;
        o.y = (acc[1] * w0 + a1[1] * w1) * invl;
        o.z = (acc[2] * w0 + a1[2] * w1) * invl;
        o.w = (acc[3] * w0 + a1[3] * w1) * invl;
        *(float4*)(out + ((size_t)bidx * SEQ + qrow) * UNITS + h * DHEAD + g * 4) = o;
    }
}

extern "C" void kernel_launch(void* const* d_in, const int* in_sizes, int n_in,
                              void* d_out, int out_size, void* d_ws, size_t ws_size,
                              hipStream_t stream) {
    const float* memory   = (const float*)d_in[0];
    const float* query    = (const float*)d_in[1];
    const int*   seq_mask = (const int*)d_in[2];
    float*       out      = (float*)d_out;
    dim3 grid(SEQ / 64, NHEADS, BATCH);
    attn_fwd<<<grid, 512, 0, stream>>>(memory, query, seq_mask, out);
}

// Round 4
// 114.465 us; speedup vs baseline: 1.0910x; 1.0910x over previous
//
#include <hip/hip_runtime.h>
#include <hip/hip_bf16.h>

#define UNITS 128
#define NHEADS 8
#define SEQ 4096
#define BATCH 2
#define KVBLK 64
#define HALFLEN (SEQ / 2)
#define NBLK2 (HALFLEN / KVBLK)
#define QSCALE 0.3606737602f   // d^-0.5 * log2(e): logits in log2 domain
#define MASKNEG -1e30f
#define MINIT   -1e4f

typedef __bf16 bf8v __attribute__((ext_vector_type(8)));
typedef float  f4v  __attribute__((ext_vector_type(4)));
typedef float  f16v __attribute__((ext_vector_type(16)));

union BF2  { __bf16 h[2]; unsigned int u; };
union FRAG { unsigned int u[4]; bf8v v; };

__device__ __forceinline__ float fmax3(float a, float b, float c) {
    return fmaxf(fmaxf(a, b), c);
}

// 32x32x16 layouts (HW-verified m74/m101): A[row=lane&31][k=(lane>>5)*8+j],
// B[k=(lane>>5)*8+j][col=lane&31], C/D col=lane&31, row=(reg&3)+8*(reg>>2)+4*(lane>>5)

__global__ __launch_bounds__(256, 4) void attn_fwd(
    const float* __restrict__ memory, const float* __restrict__ query,
    const int* __restrict__ seq_mask, float* __restrict__ out)
{
    const int bidx = blockIdx.z, hh = blockIdx.y, qblk = blockIdx.x;
    const int tid  = threadIdx.x;
    const int wave = tid >> 6, qt = wave & 1, half = wave >> 1;
    const int lane = tid & 63, col = lane & 31, hl = lane >> 5;

    __shared__ __bf16 Klds[2][2][KVBLK][16];   // 8 KB; byte ^= (key&7)<<4
    __shared__ __bf16 Vt[2][2][32][KVBLK];     // 16 KB; byte ^= (d&7)<<4; rows 16-31 const
    __shared__ float  maskadd[2][2][KVBLK];    // 1 KB
    __shared__ float  mrg[2][32][20];          // 5 KB (epilogue merge)

    // ---- init Vt rows 16..31 once: row16 = 1.0 (free denominator), others 0
    for (int i = tid; i < 2 * 2 * 16 * KVBLK; i += 256) {
        const int key = i & 63, row = 16 + ((i >> 6) & 15), hb = i >> 10;
        char* base = (char*)&Vt[hb >> 1][hb & 1][0][0];
        int b = row * 128 + key * 2;
        b ^= (row & 7) << 4;
        *(__bf16*)(base + b) = (row == 16) ? (__bf16)1.0f : (__bf16)0.0f;
    }

    // ---- Q fragment (B operand): k = d = hl*8+j, all 16 real (K=16 exactly)
    const int qrow = qblk * 64 + qt * 32 + col;
    bf8v qfrag;
    {
        const float* qp = query + ((size_t)bidx * SEQ + qrow) * UNITS + hh * 16 + hl * 8;
        #pragma unroll
        for (int j = 0; j < 8; ++j) qfrag[j] = (__bf16)(qp[j] * QSCALE);
    }

    // ---- staging assignments (128 threads per kv-half)
    const int t128 = tid & 127;
    const int skey = t128 >> 1, spart = t128 & 1;   // K: one key, 8 d's
    const int vkp  = t128 & 31, vdp = t128 >> 5;    // V: keys 2vkp,2vkp+1 x d vdp*4..+3

    const size_t membase = (size_t)bidx * SEQ * (2 * UNITS);
    const float* kp = memory + membase + (size_t)(half * HALFLEN + skey) * (2 * UNITS) + hh * 16 + spart * 8;
    const float* vp = memory + membase + (size_t)(half * HALFLEN + 2 * vkp) * (2 * UNITS) + UNITS + hh * 16 + vdp * 4;
    const int*   mp = seq_mask + (size_t)bidx * SEQ + half * HALFLEN + (t128 & 63);

    f4v ka = *(const f4v*)kp;
    f4v kb = *(const f4v*)(kp + 4);
    f4v va = *(const f4v*)vp;
    f4v vb = *(const f4v*)(vp + 2 * UNITS);
    int mreg = (t128 < KVBLK) ? *mp : 0;

    float m = MINIT;
    f16v acc;
    #pragma unroll
    for (int i = 0; i < 16; ++i) acc[i] = 0.f;

    for (int blk = 0; blk < NBLK2; ++blk) {
        const int buf = blk & 1;
        char* kbase = (char*)&Klds[half][buf][0][0];
        char* vbase = (char*)&Vt[half][buf][0][0];

        // ---- staged regs -> LDS
        {
            bf8v k8;
            #pragma unroll
            for (int i = 0; i < 4; ++i) { k8[i] = (__bf16)ka[i]; k8[4 + i] = (__bf16)kb[i]; }
            int b = skey * 32 + spart * 16;
            b ^= (skey & 7) << 4;
            *(bf8v*)(kbase + b) = k8;
            #pragma unroll
            for (int i = 0; i < 4; ++i) {
                BF2 p; p.h[0] = (__bf16)va[i]; p.h[1] = (__bf16)vb[i];
                const int d = vdp * 4 + i;
                int bb = d * 128 + vkp * 4;
                bb ^= (d & 7) << 4;
                *(unsigned int*)(vbase + bb) = p.u;
            }
            if (t128 < KVBLK) maskadd[half][buf][t128] = mreg ? 0.f : MASKNEG;
        }

        __syncthreads();

        // ---- prefetch next block (lands under compute)
        if (blk + 1 < NBLK2) {
            kp += KVBLK * 2 * UNITS;
            vp += KVBLK * 2 * UNITS;
            mp += KVBLK;
            ka = *(const f4v*)kp;
            kb = *(const f4v*)(kp + 4);
            va = *(const f4v*)vp;
            vb = *(const f4v*)(vp + 2 * UNITS);
            if (t128 < KVBLK) mreg = *mp;
        }

        // ---- QK^T (swapped): D[key][q], mask in C operand
        f16v sv0, sv1;
        #pragma unroll
        for (int s = 0; s < 2; ++s) {
            const int key = s * 32 + col;
            int b = key * 32 + hl * 16;
            b ^= (key & 7) << 4;
            bf8v kfrag = *(bf8v*)(kbase + b);
            const float* mm = &maskadd[half][buf][0] + s * 32 + 4 * hl;
            f4v c0 = *(const f4v*)(mm);
            f4v c1 = *(const f4v*)(mm + 8);
            f4v c2 = *(const f4v*)(mm + 16);
            f4v c3 = *(const f4v*)(mm + 24);
            f16v cma;
            #pragma unroll
            for (int i = 0; i < 4; ++i) {
                cma[i] = c0[i]; cma[4 + i] = c1[i]; cma[8 + i] = c2[i]; cma[12 + i] = c3[i];
            }
            f16v r = __builtin_amdgcn_mfma_f32_32x32x16_bf16(kfrag, qfrag, cma, 0, 0, 0);
            if (s == 0) sv0 = r; else sv1 = r;
        }

        // ---- block max: pairwise + max3 tree + 1 shfl
        float c[16];
        #pragma unroll
        for (int i = 0; i < 16; ++i) c[i] = fmaxf(sv0[i], sv1[i]);
        float r0 = fmax3(c[0], c[1], c[2]);
        float r1 = fmax3(c[3], c[4], c[5]);
        float r2 = fmax3(c[6], c[7], c[8]);
        float r3 = fmax3(c[9], c[10], c[11]);
        float r4 = fmax3(c[12], c[13], c[14]);
        float bmax = fmaxf(fmax3(r0, r1, r2), fmax3(r3, r4, c[15]));
        bmax = fmaxf(bmax, __shfl_xor(bmax, 32));

        // ---- T13 defer-max (log2 domain): acc[8] is the running denominator
        if (!__all(bmax <= m + 11.0f)) {
            const float m_new = fmaxf(m, bmax);
            const float sc = exp2f(m - m_new);
            #pragma unroll
            for (int r = 0; r < 9; ++r) acc[r] *= sc;
            m = m_new;
        }

        // ---- exp2 + pack P to bf16 dwords
        #pragma unroll
        for (int i = 0; i < 16; ++i) sv0[i] = exp2f(sv0[i] - m);
        #pragma unroll
        for (int i = 0; i < 16; ++i) sv1[i] = exp2f(sv1[i] - m);
        unsigned int pk0[4][2], pk1[4][2];
        #pragma unroll
        for (int R = 0; R < 4; ++R) {
            #pragma unroll
            for (int p = 0; p < 2; ++p) {
                BF2 a; a.h[0] = (__bf16)sv0[4 * R + 2 * p]; a.h[1] = (__bf16)sv0[4 * R + 2 * p + 1];
                pk0[R][p] = a.u;
                BF2 b2; b2.h[0] = (__bf16)sv1[4 * R + 2 * p]; b2.h[1] = (__bf16)sv1[4 * R + 2 * p + 1];
                pk1[R][p] = b2.u;
            }
        }

        // ---- PV: in-register P->B-frag redistribution (1 shfl pair per chunk)
        // B-frag chunk ck needs keys 16ck+8hl+j, q=col; source reg-group R=2*(ck&1)+hl
        #pragma unroll
        for (int ck = 0; ck < 4; ++ck) {
            const int c2 = ck & 1;
            unsigned int own0, own1, snd0, snd1;
            if ((ck >> 1) == 0) {
                own0 = hl ? pk0[2 * c2 + 1][0] : pk0[2 * c2][0];
                own1 = hl ? pk0[2 * c2 + 1][1] : pk0[2 * c2][1];
                snd0 = hl ? pk0[2 * c2][0]     : pk0[2 * c2 + 1][0];
                snd1 = hl ? pk0[2 * c2][1]     : pk0[2 * c2 + 1][1];
            } else {
                own0 = hl ? pk1[2 * c2 + 1][0] : pk1[2 * c2][0];
                own1 = hl ? pk1[2 * c2 + 1][1] : pk1[2 * c2][1];
                snd0 = hl ? pk1[2 * c2][0]     : pk1[2 * c2 + 1][0];
                snd1 = hl ? pk1[2 * c2][1]     : pk1[2 * c2 + 1][1];
            }
            const unsigned int x0 = (unsigned int)__shfl_xor((int)snd0, 32);
            const unsigned int x1 = (unsigned int)__shfl_xor((int)snd1, 32);
            FRAG pf;
            pf.u[0] = hl ? x0 : own0;
            pf.u[1] = hl ? x1 : own1;
            pf.u[2] = hl ? own0 : x0;
            pf.u[3] = hl ? own1 : x1;
            int b = col * 128 + ck * 32 + hl * 16;
            b ^= (col & 7) << 4;
            bf8v vfrag = *(bf8v*)(vbase + b);
            acc = __builtin_amdgcn_mfma_f32_32x32x16_bf16(vfrag, pf.v, acc, 0, 0, 0);
        }
    }

    // ---- epilogue: denominator from V-row-16 trick, then kv-half merge via LDS
    const float l = acc[8] + __shfl_xor(acc[8], 32);

    if (half == 1) {
        f4v w0v, w1v;
        #pragma unroll
        for (int i = 0; i < 4; ++i) { w0v[i] = acc[i]; w1v[i] = acc[4 + i]; }
        *(f4v*)&mrg[qt][col][4 * hl]     = w0v;   // d rows 4hl..4hl+3
        *(f4v*)&mrg[qt][col][8 + 4 * hl] = w1v;   // d rows 8+4hl..11+4hl
        if (hl == 0) { mrg[qt][col][16] = l; mrg[qt][col][17] = m; }
    }
    __syncthreads();
    if (half == 0) {
        const float l1 = mrg[qt][col][16];
        const float m1 = mrg[qt][col][17];
        f4v a1 = *(const f4v*)&mrg[qt][col][4 * hl];
        f4v a2 = *(const f4v*)&mrg[qt][col][8 + 4 * hl];
        const float M  = fmaxf(m, m1);
        const float w0 = exp2f(m - M), w1 = exp2f(m1 - M);
        const float invl = 1.0f / (l * w0 + l1 * w1);
        float* op = out + ((size_t)bidx * SEQ + qrow) * UNITS + hh * 16;
        f4v o0, o1;
        #pragma unroll
        for (int i = 0; i < 4; ++i) {
            o0[i] = (acc[i]     * w0 + a1[i] * w1) * invl;
            o1[i] = (acc[4 + i] * w0 + a2[i] * w1) * invl;
        }
        *(f4v*)(op + 4 * hl)     = o0;
        *(f4v*)(op + 8 + 4 * hl) = o1;
    }
}

extern "C" void kernel_launch(void* const* d_in, const int* in_sizes, int n_in,
                              void* d_out, int out_size, void* d_ws, size_t ws_size,
                              hipStream_t stream) {
    const float* memory   = (const float*)d_in[0];
    const float* query    = (const float*)d_in[1];
    const int*   seq_mask = (const int*)d_in[2];
    float*       out      = (float*)d_out;
    dim3 grid(SEQ / 64, NHEADS, BATCH);
    attn_fwd<<<grid, 256, 0, stream>>>(memory, query, seq_mask, out);
}